// Round 6
// baseline (436.267 us; speedup 1.0000x reference)
//
#include <hip/hip_runtime.h>

// LengthRegulator: B=64, C=384, T=512 -> MAX_NEW_TIME=4096, dur in [0,8).
// Single fused kernel: each block scans the duration row of its batch
// (redundant but ~free), builds the inverse index table in LDS, then does
// the LDS-staged expand-gather over 3 channel-tiles of 8 rows each.
// Frame t owns output positions [csum[t-1], csum[t]); tail reads a zeroed
// LDS pad via sentinel byte-offset. Mask = (out[b,0,j] != 0) as f32 0/1.

#define BB 64
#define CC 384
#define TT 512
#define TOUT 4096
#define CB 8           // channels per tile
#define ROW4 129       // row stride in float4 (128 data + 1 zero pad)
#define ROWF (ROW4*4)  // row stride floats = 516; sentinel byte-offset 2048
#define TILES 3        // tiles per block: 24 channels; grid.x = 384/24 = 16

__global__ __launch_bounds__(256) void lr_fused_kernel(
    const float* __restrict__ x, const int* __restrict__ dur,
    float* __restrict__ out, float* __restrict__ mask) {
  const int b = blockIdx.y;
  const int tid = threadIdx.x;
  const int lane = tid & 63;
  const int wv = tid >> 6;

  __shared__ int tbl[TOUT];        // 16 KB: LDS byte-offset per output pos
  __shared__ float xs[CB * ROWF];  // 16.5 KB: x tile, padded rows
  __shared__ int wsum[4];

  // ---- duration scan: 2 frames per thread, shuffle scan + wave combine ----
  const int2 d2 = *(const int2*)(dur + b * TT + tid * 2);
  int v = d2.x + d2.y;
  #pragma unroll
  for (int off = 1; off < 64; off <<= 1) {
    int u = __shfl_up(v, off, 64);
    if (lane >= off) v += u;
  }
  if (lane == 63) wsum[wv] = v;

  // Init table to sentinel (pad slot at float index 512 -> byte 2048)
  #pragma unroll
  for (int k = 0; k < TOUT / 256; ++k) tbl[tid + k * 256] = TT * 4;
  __syncthreads();

  int base = 0;
  #pragma unroll
  for (int w = 0; w < 4; ++w) base += (w < wv) ? wsum[w] : 0;
  const int end1 = v + base;          // inclusive csum at frame 2*tid+1
  const int start1 = end1 - d2.y;
  const int start0 = start1 - d2.x;   // = csum[2*tid-1]

  // Scatter byte offsets (disjoint segments, <8 writes per frame)
  for (int p = start0; p < start1; ++p) tbl[p] = (tid * 2) << 2;
  for (int p = start1; p < end1; ++p) tbl[p] = (tid * 2 + 1) << 2;
  __syncthreads();

  // This thread's 16 output positions as LDS byte offsets
  int4 O[TOUT / 1024];
  #pragma unroll
  for (int jt = 0; jt < TOUT / 1024; ++jt)
    O[jt] = *(const int4*)(tbl + jt * 1024 + tid * 4);

  float4* __restrict__ xs4 = (float4*)xs;
  const char* __restrict__ xsb = (const char*)xs;

  #pragma unroll
  for (int s = 0; s < TILES; ++s) {
    const int c0 = (blockIdx.x * TILES + s) * CB;
    __syncthreads();  // protect xs from previous tile's readers

    // Stage x tile: 1024 data float4s, coalesced, row-remapped to stride 129.
    const float4* __restrict__ xb4 =
        (const float4*)(x + ((size_t)b * CC + c0) * TT);
    #pragma unroll
    for (int k = 0; k < (CB * TT / 4) / 256; ++k) {
      const int k2 = k * 256 + tid;
      xs4[(k2 >> 7) * ROW4 + (k2 & 127)] = xb4[k2];
    }
    if (tid < CB) xs4[tid * ROW4 + 128] = make_float4(0.f, 0.f, 0.f, 0.f);
    __syncthreads();

    float* __restrict__ ob = out + ((size_t)b * CC + c0) * TOUT + tid * 4;

    #pragma unroll
    for (int c = 0; c < CB; ++c) {
      const char* __restrict__ xrc = xsb + c * (ROWF * 4);
      #pragma unroll
      for (int jt = 0; jt < TOUT / 1024; ++jt) {
        const int4 o = O[jt];
        float4 vv;
        vv.x = *(const float*)(xrc + o.x);
        vv.y = *(const float*)(xrc + o.y);
        vv.z = *(const float*)(xrc + o.z);
        vv.w = *(const float*)(xrc + o.w);
        *(float4*)(ob + (size_t)c * TOUT + jt * 1024) = vv;

        if (c == 0 && c0 == 0) {
          float4 m;
          m.x = (vv.x != 0.0f) ? 1.0f : 0.0f;
          m.y = (vv.y != 0.0f) ? 1.0f : 0.0f;
          m.z = (vv.z != 0.0f) ? 1.0f : 0.0f;
          m.w = (vv.w != 0.0f) ? 1.0f : 0.0f;
          *(float4*)(mask + (size_t)b * TOUT + jt * 1024 + tid * 4) = m;
        }
      }
    }
  }
}

extern "C" void kernel_launch(void* const* d_in, const int* in_sizes, int n_in,
                              void* d_out, int out_size, void* d_ws, size_t ws_size,
                              hipStream_t stream) {
  const float* x = (const float*)d_in[0];       // (B, C, T) f32
  const int* dur = (const int*)d_in[1];         // (B, 1, T) i32

  float* out = (float*)d_out;                   // (B, C, TOUT) f32
  float* mask = out + (size_t)BB * CC * TOUT;   // (B, 1, TOUT) as f32 0/1

  lr_fused_kernel<<<dim3(CC / CB / TILES, BB), 256, 0, stream>>>(
      x, dur, out, mask);
}